// Round 1
// baseline (51.793 us; speedup 1.0000x reference)
//
#include <hip/hip_runtime.h>
#include <hip/hip_bf16.h>

typedef int v4i __attribute__((ext_vector_type(4)));

#define HWSZ 3136   // 56*56
#define IMW  56
#define CIN  64
#define COUT 128

__device__ __forceinline__ float step_size(float a) {
    a = a > 0.f ? a : 0.f;              // relu(alpha)
    return 2.0f * a / 254.0f;           // matches ref rounding
}

__device__ __forceinline__ int quant1(float x, float s) {
    float v = rintf(x / s);             // round-half-even like jnp.round
    v = fminf(127.f, fmaxf(-127.f, v)); // clip(-127, 127)
    return (int)v;
}

// ---------------- quantize x: NCHW fp32 -> NHWC int8 ----------------
// grid: 32 n * 49 hw-tiles = 1568 blocks, 256 threads
__global__ __launch_bounds__(256) void qx_kernel(const float* __restrict__ x,
                                                 const float* __restrict__ alpha,
                                                 signed char* __restrict__ cx) {
    __shared__ signed char tile[64 * 68];   // 64 hw x 64 c, stride 68 to break banks
    float s = step_size(alpha[0]);
    int n   = blockIdx.x / 49;
    int hw0 = (blockIdx.x % 49) * 64;
    int t   = threadIdx.x;
    int hwl = t & 63;       // coalesced along hw
    int cb  = t >> 6;       // 0..3

    const float* xb = x + (size_t)n * (CIN * HWSZ) + hw0 + hwl;
#pragma unroll
    for (int i = 0; i < 16; ++i) {
        int c = cb * 16 + i;
        float v = xb[(size_t)c * HWSZ];
        tile[hwl * 68 + c] = (signed char)quant1(v, s);
    }
    __syncthreads();

    // write out: thread t -> pixel p = t>>2, 16-byte segment seg = t&3
    int p = t >> 2, seg = t & 3;
    const unsigned int* lp = (const unsigned int*)tile;
    int base = (p * 68 + seg * 16) >> 2;    // dword index (68,16 both /4)
    v4i val;
    val[0] = (int)lp[base + 0];
    val[1] = (int)lp[base + 1];
    val[2] = (int)lp[base + 2];
    val[3] = (int)lp[base + 3];
    *(v4i*)(cx + (size_t)(n * HWSZ + hw0 + p) * 64 + seg * 16) = val;
}

// ---------------- quantize w: [o][c][3][3] fp32 -> wt[o][tap][c] int8 ----------------
// 73728 elements, 288 blocks x 256
__global__ __launch_bounds__(256) void qw_kernel(const float* __restrict__ w,
                                                 const float* __restrict__ alpha,
                                                 signed char* __restrict__ wt) {
    float s = step_size(alpha[0]);
    int j = blockIdx.x * 256 + threadIdx.x;   // wt flat index
    int o = j / 576;
    int r = j % 576;
    int tap = r >> 6;
    int c   = r & 63;
    float v = w[((size_t)o * 64 + c) * 9 + tap];
    wt[j] = (signed char)quant1(v, s);
}

// ---------------- int8 implicit-GEMM conv ----------------
// M = 100352 pixels, N = 128 out-channels, K = 576 = 9 taps * 64 ch
// block = 256 (4 waves); each wave: 32 pixels x 128 o; block: 128 pixels
// grid = 100352/128 = 784
__global__ __launch_bounds__(256) void conv_kernel(const signed char* __restrict__ cx,
                                                   const signed char* __restrict__ wt,
                                                   const float* __restrict__ ax,
                                                   const float* __restrict__ aw,
                                                   float* __restrict__ out) {
    float scale = step_size(ax[0]) * step_size(aw[0]);
    int tid  = threadIdx.x;
    int lane = tid & 63;
    int wid  = tid >> 6;
    int pr   = lane & 15;   // A: o-row within 16-tile, B: pixel within 16-tile
    int kg   = lane >> 4;   // 16-byte chunk within K=64 tap
    int m0   = (blockIdx.x * 4 + wid) * 32;

    int pA = m0 + pr;
    int pB = m0 + 16 + pr;
    int nA = pA / HWSZ, hwA = pA % HWSZ, hA = hwA / IMW, wA = hwA % IMW;
    int nB = pB / HWSZ, hwB = pB % HWSZ, hB = hwB / IMW, wB = hwB % IMW;

    const signed char* xA = cx + (size_t)nA * HWSZ * 64;
    const signed char* xB = cx + (size_t)nB * HWSZ * 64;

    v4i acc[2][8] = {};

#pragma unroll
    for (int tap = 0; tap < 9; ++tap) {
        int dh = tap / 3 - 1, dw = tap % 3 - 1;
        int yA = hA + dh, xwA = wA + dw;
        int yB = hB + dh, xwB = wB + dw;
        v4i b0 = {0, 0, 0, 0}, b1 = {0, 0, 0, 0};
        if ((unsigned)yA < 56u && (unsigned)xwA < 56u)
            b0 = *(const v4i*)(xA + ((yA * IMW + xwA) * 64) + kg * 16);
        if ((unsigned)yB < 56u && (unsigned)xwB < 56u)
            b1 = *(const v4i*)(xB + ((yB * IMW + xwB) * 64) + kg * 16);
#pragma unroll
        for (int ot = 0; ot < 8; ++ot) {
            v4i a = *(const v4i*)(wt + ((ot * 16 + pr) * 9 + tap) * 64 + kg * 16);
            acc[0][ot] = __builtin_amdgcn_mfma_i32_16x16x64_i8(a, b0, acc[0][ot], 0, 0, 0);
            acc[1][ot] = __builtin_amdgcn_mfma_i32_16x16x64_i8(a, b1, acc[1][ot], 0, 0, 0);
        }
    }

    // epilogue: D mapping col=lane&15 (pixel), row=(lane>>4)*4+reg (o)
#pragma unroll
    for (int ot = 0; ot < 8; ++ot) {
#pragma unroll
        for (int r = 0; r < 4; ++r) {
            int o = ot * 16 + kg * 4 + r;
            out[((size_t)nA * COUT + o) * HWSZ + hwA] = scale * (float)acc[0][ot][r];
            out[((size_t)nB * COUT + o) * HWSZ + hwB] = scale * (float)acc[1][ot][r];
        }
    }
}

extern "C" void kernel_launch(void* const* d_in, const int* in_sizes, int n_in,
                              void* d_out, int out_size, void* d_ws, size_t ws_size,
                              hipStream_t stream) {
    const float* x  = (const float*)d_in[0];
    const float* w  = (const float*)d_in[1];
    const float* ax = (const float*)d_in[2];
    const float* aw = (const float*)d_in[3];
    float* out = (float*)d_out;

    signed char* cx = (signed char*)d_ws;              // 32*3136*64 = 6,422,528 B
    signed char* wt = cx + 6422528;                    // 128*9*64  =    73,728 B

    qx_kernel<<<1568, 256, 0, stream>>>(x, ax, cx);
    qw_kernel<<<288, 256, 0, stream>>>(w, aw, wt);
    conv_kernel<<<784, 256, 0, stream>>>(cx, wt, ax, aw, out);
}

// Round 2
// 42.604 us; speedup vs baseline: 1.2157x; 1.2157x over previous
//
#include <hip/hip_runtime.h>
#include <hip/hip_bf16.h>

typedef int v4i __attribute__((ext_vector_type(4)));

#define HWSZ 3136   // 56*56
#define IMW  56
#define CIN  64
#define COUT 128

__device__ __forceinline__ float step_size(float a) {
    a = a > 0.f ? a : 0.f;              // relu(alpha)
    return 2.0f * a / 254.0f;
}

__device__ __forceinline__ int quant1(float x, float s) {
    float v = rintf(x / s);             // round-half-even like jnp.round
    v = fminf(127.f, fmaxf(-127.f, v)); // clip(-127, 127)
    return (int)v;
}

// ---------------- fused quantize: x NCHW->NHWC int8, w OIHW -> wt[o][tap][c] ----------------
// blocks 0..1567: x tiles (32 n * 49 hw-tiles). blocks 1568..1855: w.
__global__ __launch_bounds__(256) void quant_kernel(const float* __restrict__ x,
                                                    const float* __restrict__ w,
                                                    const float* __restrict__ alpha_x,
                                                    const float* __restrict__ alpha_w,
                                                    signed char* __restrict__ cx,
                                                    signed char* __restrict__ wt) {
    int t = threadIdx.x;
    if (blockIdx.x >= 1568) {
        float s = step_size(alpha_w[0]);
        int j = (blockIdx.x - 1568) * 256 + t;   // wt flat index, 73728 total
        int o = j / 576;
        int r = j % 576;
        int tap = r >> 6;
        int c   = r & 63;
        float v = w[((size_t)o * 64 + c) * 9 + tap];
        wt[j] = (signed char)quant1(v, s);
        return;
    }
    __shared__ signed char tile[64 * 68];
    float s = step_size(alpha_x[0]);
    int n   = blockIdx.x / 49;
    int hw0 = (blockIdx.x % 49) * 64;
    int hwl = t & 63;
    int cb  = t >> 6;

    const float* xb = x + (size_t)n * (CIN * HWSZ) + hw0 + hwl;
#pragma unroll
    for (int i = 0; i < 16; ++i) {
        int c = cb * 16 + i;
        float v = xb[(size_t)c * HWSZ];
        tile[hwl * 68 + c] = (signed char)quant1(v, s);
    }
    __syncthreads();

    int p = t >> 2, seg = t & 3;
    const unsigned int* lp = (const unsigned int*)tile;
    int base = (p * 68 + seg * 16) >> 2;
    v4i val;
    val[0] = (int)lp[base + 0];
    val[1] = (int)lp[base + 1];
    val[2] = (int)lp[base + 2];
    val[3] = (int)lp[base + 3];
    *(v4i*)(cx + (size_t)(n * HWSZ + hw0 + p) * 64 + seg * 16) = val;
}

// ---------------- int8 implicit-GEMM conv ----------------
// M = 100352 pixels (A rows), N = 128 out-ch (B cols), K = 576 = 9 taps * 64 ch
// block = 256 (4 waves) -> 128 px x 128 o; wave = 64 px x 64 o (2x2 wave grid)
// grid = 100352/128 = 784
__global__ __launch_bounds__(256) void conv_kernel(const signed char* __restrict__ cx,
                                                   const signed char* __restrict__ wt,
                                                   const float* __restrict__ ax,
                                                   const float* __restrict__ aw,
                                                   float* __restrict__ out) {
    float scale = step_size(ax[0]) * step_size(aw[0]);
    int tid  = threadIdx.x;
    int lane = tid & 63;
    int wid  = tid >> 6;
    int row  = lane & 15;   // A: pixel within 16-tile; B: o within 16-tile
    int kg   = lane >> 4;   // 16-byte k-chunk within the tap's 64 channels
    int wp   = wid >> 1;    // pixel half of block tile
    int wo   = wid & 1;     // o half of block tile
    int pbase = blockIdx.x * 128 + wp * 64;
    int obase = wo * 64;

    // per-pixel-tile coords for the A loads
    int ph[4], pw[4];
    const signed char* xb[4];
#pragma unroll
    for (int pt = 0; pt < 4; ++pt) {
        int p  = pbase + pt * 16 + row;
        int n  = p / HWSZ;
        int hw = p % HWSZ;
        ph[pt] = hw / IMW;
        pw[pt] = hw % IMW;
        xb[pt] = cx + (size_t)n * HWSZ * 64 + kg * 16;
    }

    v4i acc[4][4] = {};

#pragma unroll
    for (int tap = 0; tap < 9; ++tap) {
        int dh = tap / 3 - 1, dw = tap % 3 - 1;
        v4i a[4];
#pragma unroll
        for (int pt = 0; pt < 4; ++pt) {
            int y = ph[pt] + dh, xq = pw[pt] + dw;
            v4i v = {0, 0, 0, 0};
            if ((unsigned)y < 56u && (unsigned)xq < 56u)
                v = *(const v4i*)(xb[pt] + (y * IMW + xq) * 64);
            a[pt] = v;
        }
        v4i b[4];
#pragma unroll
        for (int ot = 0; ot < 4; ++ot)
            b[ot] = *(const v4i*)(wt + ((size_t)(obase + ot * 16 + row) * 9 + tap) * 64 + kg * 16);
#pragma unroll
        for (int pt = 0; pt < 4; ++pt)
#pragma unroll
            for (int ot = 0; ot < 4; ++ot)
                acc[pt][ot] = __builtin_amdgcn_mfma_i32_16x16x64_i8(a[pt], b[ot], acc[pt][ot], 0, 0, 0);
    }

    // epilogue: D row = (lane>>4)*4+reg = pixel, col = lane&15 = o
#pragma unroll
    for (int pt = 0; pt < 4; ++pt) {
        int p4 = pbase + pt * 16 + kg * 4;   // 4 consecutive pixels (4-aligned, same n)
        int n  = p4 / HWSZ;
        int hw = p4 % HWSZ;
#pragma unroll
        for (int ot = 0; ot < 4; ++ot) {
            int o = obase + ot * 16 + row;
            float4 v;
            v.x = scale * (float)acc[pt][ot][0];
            v.y = scale * (float)acc[pt][ot][1];
            v.z = scale * (float)acc[pt][ot][2];
            v.w = scale * (float)acc[pt][ot][3];
            *(float4*)(out + ((size_t)n * COUT + o) * HWSZ + hw) = v;
        }
    }
}

extern "C" void kernel_launch(void* const* d_in, const int* in_sizes, int n_in,
                              void* d_out, int out_size, void* d_ws, size_t ws_size,
                              hipStream_t stream) {
    const float* x  = (const float*)d_in[0];
    const float* w  = (const float*)d_in[1];
    const float* ax = (const float*)d_in[2];
    const float* aw = (const float*)d_in[3];
    float* out = (float*)d_out;

    signed char* cx = (signed char*)d_ws;   // 32*3136*64 = 6,422,528 B
    signed char* wt = cx + 6422528;         // 128*9*64   =    73,728 B

    quant_kernel<<<1856, 256, 0, stream>>>(x, w, ax, aw, cx, wt);
    conv_kernel<<<784, 256, 0, stream>>>(cx, wt, ax, aw, out);
}